// Round 1
// 204.837 us; speedup vs baseline: 1.0297x; 1.0297x over previous
//
#include <hip/hip_runtime.h>

#define NUM_USERS 100000
#define H1 256
#define H2 128
#define H3 64
#define BATCH 1024

// One block per batch row; whole grid co-resident (4 blocks/CU), so kernel
// time ~= one block's serial latency. This version attacks that latency:
//  - L2: all 256 threads active (2 threads per output, K split in halves),
//        4 independent accumulators, float4 LDS broadcast reads, full unroll.
//  - L3: all 256 threads active (4 threads per output, K split in quarters).
//  - L4: fused into L3's combine as a 64-lane shuffle tree (6 dependent steps
//        instead of thread-0's 64 dependent LDS-latency iterations).
// All phases barrier-separated; every LDS access is broadcast or stride-1
// (no bank conflicts); all indices statically in bounds; fully deterministic.
__global__ __launch_bounds__(256) void mlp_row(
    const int* __restrict__ user_ids,
    const int* __restrict__ item_ids,
    const float* __restrict__ W1, const float* __restrict__ b1,
    const float* __restrict__ W2, const float* __restrict__ b2,
    const float* __restrict__ W3, const float* __restrict__ b3,
    const float* __restrict__ W4, const float* __restrict__ b4,
    float* __restrict__ out)
{
    __shared__ __align__(16) float h1[H1];   // 256
    __shared__ __align__(16) float p2[256];  // layer-2 partials
    __shared__ __align__(16) float h2[H2];   // 128
    __shared__ __align__(16) float p3[256];  // layer-3 partials

    const int t   = threadIdx.x;   // 0..255
    const int row = blockIdx.x;    // 0..1023

    const int u  = user_ids[row];  // wave-uniform
    const int it = item_ids[row];

    // ---- Layer 1: h1[t] = relu(W1[u][t] + W1[NU+it][t] + b1[t])
    {
        float v = W1[(size_t)u * H1 + t]
                + W1[(size_t)(NUM_USERS + it) * H1 + t]
                + b1[t];
        h1[t] = v > 0.f ? v : 0.f;
    }
    __syncthreads();

    // ---- Layer 2: 256 threads = 128 outputs x 2 K-halves.
    //      j = t & 127 (output), half = t >> 7 selects k in [half*128, +128)
    {
        const int j  = t & (H2 - 1);
        const int k0 = (t >> 7) << 7;            // 0 or 128 (wave-uniform)
        const float4* h1v = (const float4*)(h1 + k0);
        const float* __restrict__ w2c = W2 + j;  // column j
        float a0 = 0.f, a1 = 0.f, a2 = 0.f, a3 = 0.f;
        #pragma unroll
        for (int k4 = 0; k4 < 32; ++k4) {
            const float4 h = h1v[k4];            // LDS broadcast (wave-uniform addr)
            const int kk = k0 + (k4 << 2);
            a0 = fmaf(h.x, w2c[(size_t)(kk    ) * H2], a0);
            a1 = fmaf(h.y, w2c[(size_t)(kk + 1) * H2], a1);
            a2 = fmaf(h.z, w2c[(size_t)(kk + 2) * H2], a2);
            a3 = fmaf(h.w, w2c[(size_t)(kk + 3) * H2], a3);
        }
        p2[t] = (a0 + a1) + (a2 + a3);
    }
    __syncthreads();
    if (t < H2) {
        const float s = p2[t] + p2[t + 128] + b2[t];
        h2[t] = s > 0.f ? s : 0.f;
    }
    __syncthreads();

    // ---- Layer 3: 256 threads = 64 outputs x 4 K-quarters.
    //      j = t & 63 (output), quarter = t >> 6 selects k in [q*32, +32)
    {
        const int j  = t & (H3 - 1);
        const int k0 = (t >> 6) << 5;            // 0,32,64,96 (wave-uniform)
        const float4* h2v = (const float4*)(h2 + k0);
        const float* __restrict__ w3c = W3 + j;  // column j
        float a0 = 0.f, a1 = 0.f, a2 = 0.f, a3 = 0.f;
        #pragma unroll
        for (int k4 = 0; k4 < 8; ++k4) {
            const float4 h = h2v[k4];
            const int kk = k0 + (k4 << 2);
            a0 = fmaf(h.x, w3c[(size_t)(kk    ) * H3], a0);
            a1 = fmaf(h.y, w3c[(size_t)(kk + 1) * H3], a1);
            a2 = fmaf(h.z, w3c[(size_t)(kk + 2) * H3], a2);
            a3 = fmaf(h.w, w3c[(size_t)(kk + 3) * H3], a3);
        }
        p3[t] = (a0 + a1) + (a2 + a3);
    }
    __syncthreads();

    // ---- Layer 3 combine + Layer 4, fused in wave 0 (lanes 0..63).
    if (t < H3) {
        const float s = ((p3[t] + p3[t + 64]) + (p3[t + 128] + p3[t + 192]))
                      + b3[t];
        const float h3v = s > 0.f ? s : 0.f;
        float pv = h3v * W4[t];
        #pragma unroll
        for (int off = 32; off > 0; off >>= 1)
            pv += __shfl_down(pv, off, 64);      // 6-step tree across the wave
        if (t == 0)
            out[row] = pv + b4[0];
    }
}

extern "C" void kernel_launch(void* const* d_in, const int* in_sizes, int n_in,
                              void* d_out, int out_size, void* d_ws, size_t ws_size,
                              hipStream_t stream) {
    const int*   user_ids = (const int*)d_in[0];
    const int*   item_ids = (const int*)d_in[1];
    const float* W1 = (const float*)d_in[2];
    const float* b1 = (const float*)d_in[3];
    const float* W2 = (const float*)d_in[4];
    const float* b2 = (const float*)d_in[5];
    const float* W3 = (const float*)d_in[6];
    const float* b3 = (const float*)d_in[7];
    const float* W4 = (const float*)d_in[8];
    const float* b4 = (const float*)d_in[9];
    float* out = (float*)d_out;

    dim3 grid(BATCH);   // one block per row
    dim3 block(256);
    mlp_row<<<grid, block, 0, stream>>>(user_ids, item_ids,
                                        W1, b1, W2, b2, W3, b3, W4, b4, out);
}